// Round 6
// baseline (1753.840 us; speedup 1.0000x reference)
//
#include <hip/hip_runtime.h>
#include <math.h>

// B=2 N=128 D=128 DE=64 H=8 DH=32 DI=256 DMI=512 S=5 SDI=1280 FFD=512
// Workspace offsets (float units):
#define OFF_Q    0         // (B*N,256)  hi@Wq
#define OFF_K    65536     // (B*N,256)  hj@Wk
#define OFF_A1V  131072    // (B*N,512)  silu(hj@Wv1+bv1)
#define OFF_A1P  262144    // (B*N,512)  silu(hj@Wp1+bp1)
#define OFF_V    393216    // (B*N,1280) a1v@Wv2+bv2
#define OFF_PV   720896    // (B*N,1280) a1p@Wp2+bp2
#define OFF_VW   1048576   // (B*N,5,8,128) v folded through Wcomb
#define OFF_QK   2359296   // (B*N,1024) [q1(192) q2(320) k1(192) k2(320)]
#define OFF_T    2621440   // (B,N,N,128) t
#define OFF_DEN  6815744   // (B*N,40)  den[h][s]
#define OFF_ACC  6825984   // (B*N,2,17,128) j-reduced partials
#define OFF_WEVT 7940096   // bf16 [1280 c][128 k] transposed Wev (81920 floats)
#define OFF_WCT  8022016   // bf16 [128 d][256 hd] transposed Wcomb (16384 floats)
#define OFF_HI   8038400   // (B*N,128) ln(h)*g_i
#define OFF_HJ   8071168   // (B*N,128) ln(h)*g_j
// total 8103936 floats = 32.4 MB

typedef __bf16 bf16x8 __attribute__((ext_vector_type(8)));
typedef float  f32x4  __attribute__((ext_vector_type(4)));

__device__ __forceinline__ float silu_f(float x){
  return x / (1.0f + __expf(-x));
}
__device__ __forceinline__ unsigned short f2bf(float x){
  union{float f; unsigned u;} c; c.f = x;
  unsigned r = c.u + 0x7FFFu + ((c.u >> 16) & 1u);
  return (unsigned short)(r >> 16);
}
__device__ __forceinline__ unsigned packbf(float a, float b){
  return (unsigned)f2bf(a) | ((unsigned)f2bf(b) << 16);
}
// swizzled fp32 LDS tile: row k (256B), 16B chunks XORed with (k>>2)&15
__device__ __forceinline__ void swz_store(float* Abase, int k, int j, float v){
  *(float*)((char*)Abase + k*256 + ((((j>>2) ^ ((k>>2)&15))) << 4) + ((j&3)<<2)) = v;
}
__device__ __forceinline__ f32x4 swz_load4(const float* Abase, int k, int chunk){
  return *(const f32x4*)((const char*)Abase + k*256 + ((chunk ^ ((k>>2)&15)) << 4));
}

// ---------------------------------------------------------------- K0a: LayerNorm (one row per block)
__global__ __launch_bounds__(128) void k0a_ln(
    const float* __restrict__ h, const float* __restrict__ g_i, const float* __restrict__ g_j,
    float* __restrict__ ws)
{
  __shared__ float red[2];
  const int r = blockIdx.x, tid = threadIdx.x;
  const int w = tid >> 6, l = tid & 63;
  const float hv = h[r*128 + tid];
  float s = hv;
  #pragma unroll
  for (int o = 1; o < 64; o <<= 1) s += __shfl_xor(s, o);
  if (l == 0) red[w] = s;
  __syncthreads();
  const float mu = (red[0] + red[1]) * (1.f/128.f);
  const float dv = hv - mu;
  float s2 = dv*dv;
  #pragma unroll
  for (int o = 1; o < 64; o <<= 1) s2 += __shfl_xor(s2, o);
  __syncthreads();
  if (l == 0) red[w] = s2;
  __syncthreads();
  const float rstd = 1.0f / sqrtf((red[0] + red[1])*(1.f/128.f) + 1e-5f);
  ws[OFF_HI + r*128 + tid] = dv * rstd * g_i[tid];
  ws[OFF_HJ + r*128 + tid] = dv * rstd * g_j[tid];
  if (tid < 40) ws[OFF_DEN + r*40 + tid] = 0.f;  // zero for k4 atomics
}

// ---------------------------------------------------------------- K0b: q/k/a1v/a1p (element-parallel GEMM)
__global__ __launch_bounds__(256) void k0b_qkv(
    const float* __restrict__ Wq, const float* __restrict__ Wk,
    const float* __restrict__ Wv1, const float* __restrict__ bv1,
    const float* __restrict__ Wp1, const float* __restrict__ bp1,
    float* __restrict__ ws)
{
  __shared__ float hrow[128];
  const int bid = blockIdx.x;
  const int row = bid / 6, ch = bid - 6*(bid/6);
  const int tid = threadIdx.x;
  if (tid < 128) hrow[tid] = ws[((ch == 0) ? OFF_HI : OFF_HJ) + row*128 + tid];
  __syncthreads();
  const float* W; int c; float bias = 0.f; bool act = false; float* dst; int wstride;
  switch(ch){
    case 0: W = Wq;  c = tid;      wstride = 256; dst = ws + OFF_Q   + row*256 + c; break;
    case 1: W = Wk;  c = tid;      wstride = 256; dst = ws + OFF_K   + row*256 + c; break;
    case 2: W = Wv1; c = tid;      wstride = 512; bias = bv1[c]; act = true; dst = ws + OFF_A1V + row*512 + c; break;
    case 3: W = Wv1; c = 256+tid;  wstride = 512; bias = bv1[c]; act = true; dst = ws + OFF_A1V + row*512 + c; break;
    case 4: W = Wp1; c = tid;      wstride = 512; bias = bp1[c]; act = true; dst = ws + OFF_A1P + row*512 + c; break;
    default:W = Wp1; c = 256+tid;  wstride = 512; bias = bp1[c]; act = true; dst = ws + OFF_A1P + row*512 + c; break;
  }
  float acc = bias;
  #pragma unroll 8
  for (int d = 0; d < 128; ++d) acc += hrow[d] * W[d*wstride + c];
  *dst = act ? silu_f(acc) : acc;
}

// ---------------------------------------------------------------- K0c: q1/q2/k1/k2 (one row per block)
__global__ __launch_bounds__(256) void k0c_qk12(
    const float* __restrict__ x1, const float* __restrict__ x2,
    const float* __restrict__ Wqh, const float* __restrict__ Wk1h, const float* __restrict__ Wk2h,
    float* __restrict__ ws)
{
  __shared__ float x1r[384], x2r[640];
  const int row = blockIdx.x, tid = threadIdx.x;
  for (int idx = tid; idx < 384; idx += 256) x1r[idx] = x1[row*384 + idx];
  for (int idx = tid; idx < 640; idx += 256) x2r[idx] = x2[row*640 + idx];
  __syncthreads();
  for (int idx = tid; idx < 512; idx += 256){
    if (idx < 192){
      const int e = idx/3, m = idx - e*3;
      float qa = 0.f, ka = 0.f;
      #pragma unroll 8
      for (int d = 0; d < 128; ++d){
        const float xv = x1r[d*3 + m];
        qa += xv*Wqh[d*64 + e];
        ka += xv*Wk1h[d*64 + e];
      }
      ws[OFF_QK + row*1024 + idx] = qa;
      ws[OFF_QK + row*1024 + 512 + idx] = ka;
    } else {
      const int i2 = idx - 192;
      const int e = i2/5, m = i2 - e*5;
      float qa = 0.f, ka = 0.f;
      #pragma unroll 8
      for (int d = 0; d < 128; ++d){
        const float xv = x2r[d*5 + m];
        qa += xv*Wqh[d*64 + e];
        ka += xv*Wk2h[d*64 + e];
      }
      ws[OFF_QK + row*1024 + 192 + i2] = qa;
      ws[OFF_QK + row*1024 + 704 + i2] = ka;
    }
  }
}

// ---------------------------------------------------------------- K1: v/pv GEMM (M=512,N=1280,K=512)
__global__ __launch_bounds__(256) void k1_vp(
    const float* __restrict__ Wv2, const float* __restrict__ bv2,
    const float* __restrict__ Wp2, const float* __restrict__ bp2,
    float* __restrict__ ws)
{
  __shared__ float A[512][16];   // K x rowtile (transposed)
  __shared__ float Bc[64][128];  // K-chunk x coltile
  const int tid = threadIdx.x;
  const int rt = blockIdx.x & 31;
  const int ct = blockIdx.x >> 5;
  const int r0 = rt*16;
  const bool isP = (r0 >= 256);
  const int rbase = isP ? (r0 - 256) : r0;
  const float* __restrict__ src  = ws + (isP ? OFF_A1P : OFF_A1V);
  const float* __restrict__ W    = isP ? Wp2 : Wv2;
  const float* __restrict__ bias = isP ? bp2 : bv2;
  const int c0 = ct*128;
  for (int idx = tid; idx < 2048; idx += 256){
    const int rl = idx & 15;
    const int c4 = (idx >> 4) * 4;
    const float4 v = *(const float4*)&src[(rbase+rl)*512 + c4];
    A[c4+0][rl] = v.x; A[c4+1][rl] = v.y; A[c4+2][rl] = v.z; A[c4+3][rl] = v.w;
  }
  float acc[4][2] = {{0.f}};
  const int rg = tid & 3;
  const int cg = tid >> 2;
  for (int kc = 0; kc < 8; ++kc){
    __syncthreads();
    for (int idx = tid; idx < 2048; idx += 256){
      const int kl = idx >> 5;
      const int c4 = (idx & 31)*4;
      *(float4*)&Bc[kl][c4] = *(const float4*)&W[(kc*64+kl)*1280 + c0 + c4];
    }
    __syncthreads();
    #pragma unroll 8
    for (int k = 0; k < 64; ++k){
      const float4 a = *(const float4*)&A[kc*64+k][rg*4];
      const float b0 = Bc[k][cg*2], b1 = Bc[k][cg*2+1];
      acc[0][0] += a.x*b0; acc[0][1] += a.x*b1;
      acc[1][0] += a.y*b0; acc[1][1] += a.y*b1;
      acc[2][0] += a.z*b0; acc[2][1] += a.z*b1;
      acc[3][0] += a.w*b0; acc[3][1] += a.w*b1;
    }
  }
  float* __restrict__ dst = ws + (isP ? OFF_PV : OFF_V);
  for (int rr = 0; rr < 4; ++rr)
    for (int cc = 0; cc < 2; ++cc){
      const int c = c0 + cg*2 + cc;
      dst[(rbase + rg*4 + rr)*1280 + c] = acc[rr][cc] + bias[c];
    }
}

// ---------------------------------------------------------------- K2: vW = fold v through Wcomb (one j per block)
__global__ __launch_bounds__(256) void k2_vw(const float* __restrict__ Wcomb, float* __restrict__ ws)
{
  __shared__ float vr[1280];
  const int j = blockIdx.x, tid = threadIdx.x;
  for (int idx = tid; idx < 320; idx += 256)
    *(float4*)&vr[idx*4] = *(const float4*)&ws[OFF_V + j*1280 + idx*4];
  __syncthreads();
  const int d = tid & 127;
  for (int sh = tid >> 7; sh < 40; sh += 2){
    const int s = sh >> 3, hh = sh & 7;
    float a = 0.f;
    #pragma unroll 8
    for (int dh = 0; dh < 32; ++dh)
      a += vr[s*256 + hh*32 + dh] * Wcomb[(hh*32+dh)*128 + d];
    ws[OFF_VW + j*5120 + sh*128 + d] = a;
  }
}

// ---------------------------------------------------------------- K2b: transpose-convert Wev/Wcomb to bf16
__global__ __launch_bounds__(256) void k_cvt(
    const float* __restrict__ Wev, const float* __restrict__ Wcomb, float* __restrict__ ws)
{
  __shared__ float ld[16][256];
  const int tid = threadIdx.x;
  if (blockIdx.x < 80){
    const int c0 = blockIdx.x*16;
    for (int p = 0; p < 8; ++p){
      const int idx = tid + p*256;
      const int k = idx >> 4, cl = idx & 15;
      ld[cl][k] = Wev[k*1280 + c0 + cl];
    }
    __syncthreads();
    const int cl = tid >> 4, k8 = tid & 15;
    uint4 u;
    u.x = packbf(ld[cl][k8*8+0], ld[cl][k8*8+1]);
    u.y = packbf(ld[cl][k8*8+2], ld[cl][k8*8+3]);
    u.z = packbf(ld[cl][k8*8+4], ld[cl][k8*8+5]);
    u.w = packbf(ld[cl][k8*8+6], ld[cl][k8*8+7]);
    ((uint4*)(ws + OFF_WEVT))[(c0+cl)*16 + k8] = u;
  } else {
    const int c0 = (blockIdx.x - 80)*16;
    for (int p = 0; p < 16; ++p){
      const int idx = tid + p*256;
      const int k = idx >> 4, cl = idx & 15;
      ld[cl][k] = Wcomb[k*128 + c0 + cl];
    }
    __syncthreads();
    const int cl = tid >> 4, k8i = tid & 15;
    for (int pass = 0; pass < 2; ++pass){
      const int k8 = k8i + pass*16;
      uint4 u;
      u.x = packbf(ld[cl][k8*8+0], ld[cl][k8*8+1]);
      u.y = packbf(ld[cl][k8*8+2], ld[cl][k8*8+3]);
      u.z = packbf(ld[cl][k8*8+4], ld[cl][k8*8+5]);
      u.w = packbf(ld[cl][k8*8+6], ld[cl][k8*8+7]);
      ((uint4*)(ws + OFF_WCT))[(c0+cl)*32 + k8] = u;
    }
  }
}

// ---------------------------------------------------------------- K3: t = w_ij@Wep + t_ij@Wres (fp32, streamed W)
// grid (bi,jh)=512 blocks x 512 thr. A[256k][64j] swizzled LDS; W read direct from global.
// Phase 1: w_ij -> A rows 0..127 (kst scratch aliases A rows 128..255).
// Phase 2: t_ij -> A rows 128..255. Then GEMM.
__global__ __launch_bounds__(512, 2) void k3_t(
    const float* __restrict__ t_ij, const float* __restrict__ Wep, const float* __restrict__ Wres,
    float* __restrict__ ws)
{
  __shared__ float A[16384];     // 64KB: [256 k][64 j] swizzled
  __shared__ float qrow[512];
  float* kst = A + 8192;         // 32KB flat scratch (rows 128..255 region) during phase 1
  const int tid = threadIdx.x;
  const int bi = blockIdx.x >> 1;
  const int jt = blockIdx.x & 1;
  const int j0 = jt*64;
  const int b  = bi >> 7;
  if (tid < 128) *(float4*)&qrow[tid*4] = *(const float4*)&ws[OFF_QK + bi*1024 + tid*4];
  // ---- phase 1: w_ij ----
  for (int jq = 0; jq < 4; ++jq){
    __syncthreads();
    for (int idx = tid; idx < 2048; idx += 512){   // stage 16 k-rows transposed (8192 floats)
      const int jl = idx & 15;
      const int c4 = (idx >> 4)*4;
      const float4 v = *(const float4*)&ws[OFF_QK + (b*128 + j0 + jq*16 + jl)*1024 + 512 + c4];
      kst[(c4+0)*16 + jl] = v.x; kst[(c4+1)*16 + jl] = v.y;
      kst[(c4+2)*16 + jl] = v.z; kst[(c4+3)*16 + jl] = v.w;
    }
    __syncthreads();
    for (int idx = tid; idx < 2048; idx += 512){   // w_ij[e][j] -> A rows 0..127
      const int jl = idx & 15;
      const int e  = idx >> 4;
      float acc = 0.f;
      if (e < 64){
        #pragma unroll
        for (int m = 0; m < 3; ++m) acc += qrow[e*3+m] * kst[(e*3+m)*16 + jl];
      } else {
        const int e2 = e - 64;
        #pragma unroll
        for (int m = 0; m < 5; ++m) acc += qrow[192 + e2*5+m] * kst[(192 + e2*5+m)*16 + jl];
      }
      swz_store(A, e, jq*16 + jl, acc);
    }
  }
  __syncthreads();
  // ---- phase 2: t_ij -> A rows 128..255 (transposed, swizzled) ----
  for (int idx = tid; idx < 2048; idx += 512){
    const int jl = idx >> 5;
    const int d4 = (idx & 31)*4;
    const float4 v = *(const float4*)&t_ij[(bi*128 + j0 + jl)*128 + d4];
    swz_store(A, 128+d4+0, jl, v.x);
    swz_store(A, 128+d4+1, jl, v.y);
    swz_store(A, 128+d4+2, jl, v.z);
    swz_store(A, 128+d4+3, jl, v.w);
  }
  __syncthreads();
  // main GEMM: 64j x 128c, per-thread 4j x 4c
  const int jg = tid >> 5;        // 0..15, j = jg*4+jj
  const int cg = tid & 31;        // c = cg*4
  f32x4 acc[4] = {{0,0,0,0},{0,0,0,0},{0,0,0,0},{0,0,0,0}};
  {
    const float* Wp = Wep + cg*4;
    f32x4 wv = *(const f32x4*)Wp;
    for (int k = 0; k < 127; ++k){
      const f32x4 wn = *(const f32x4*)(Wp + (k+1)*128);
      const f32x4 av = swz_load4(A, k, jg);
      acc[0] += wv*av[0]; acc[1] += wv*av[1]; acc[2] += wv*av[2]; acc[3] += wv*av[3];
      wv = wn;
    }
    const f32x4 av = swz_load4(A, 127, jg);
    acc[0] += wv*av[0]; acc[1] += wv*av[1]; acc[2] += wv*av[2]; acc[3] += wv*av[3];
  }
  {
    const float* Wp = Wres + cg*4;
    f32x4 wv = *(const f32x4*)Wp;
    for (int k = 0; k < 127; ++k){
      const f32x4 wn = *(const f32x4*)(Wp + (k+1)*128);
      const f32x4 av = swz_load4(A, 128+k, jg);
      acc[0] += wv*av[0]; acc[1] += wv*av[1]; acc[2] += wv*av[2]; acc[3] += wv*av[3];
      wv = wn;
    }
    const f32x4 av = swz_load4(A, 255, jg);
    acc[0] += wv*av[0]; acc[1] += wv*av[1]; acc[2] += wv*av[2]; acc[3] += wv*av[3];
  }
  #pragma unroll
  for (int jj = 0; jj < 4; ++jj)
    *(f32x4*)&ws[OFF_T + (bi*128 + j0 + jg*4 + jj)*128 + cg*4] = acc[jj];
}

// ---------------------------------------------------------------- K4: den (fp32, streamed Wek)
// grid 2560 = 256 bi x 2 jh x 5 cq; block 256 thr; tile 64j x 256c; per-thread 16j x 4c.
__global__ __launch_bounds__(256, 4) void k4_den(
    const float* __restrict__ Wek, float* __restrict__ ws)
{
  __shared__ float tl[8192];        // 32KB [128 k][64 j] swizzled
  __shared__ float colsum[4][256];  // 4KB
  __shared__ float den40[40];
  const int tid = threadIdx.x;
  const int bid = blockIdx.x;
  const int bi = bid / 10;
  const int rem = bid - bi*10;
  const int jh = rem & 1;
  const int cq = rem >> 1;          // s index (chunks of 256 cols = one s)
  const int j0 = jh*64;
  // stage t tile (transposed, swizzled)
  for (int idx = tid; idx < 2048; idx += 256){
    const int j = idx >> 5;
    const int d4 = (idx & 31)*4;
    const float4 v = *(const float4*)&ws[OFF_T + (bi*128 + j0 + j)*128 + d4];
    swz_store(tl, d4+0, j, v.x);
    swz_store(tl, d4+1, j, v.y);
    swz_store(tl, d4+2, j, v.z);
    swz_store(tl, d4+3, j, v.w);
  }
  if (tid < 40) den40[tid] = 0.f;
  __syncthreads();
  const int w = tid >> 6;           // j-group: rows w*16..w*16+15
  const int lane = tid & 63;        // c = lane*4
  const float* wekp = Wek + cq*256 + lane*4;
  f32x4 acc[16];
  #pragma unroll
  for (int i = 0; i < 16; ++i) acc[i] = (f32x4){0,0,0,0};
  f32x4 wv = *(const f32x4*)wekp;
  for (int k = 0; k < 127; ++k){
    const f32x4 wn = *(const f32x4*)(wekp + (k+1)*1280);
    #pragma unroll
    for (int q = 0; q < 4; ++q){
      const f32x4 tv = swz_load4(tl, k, w*4 + q);
      acc[q*4+0] += wv*tv[0]; acc[q*4+1] += wv*tv[1];
      acc[q*4+2] += wv*tv[2]; acc[q*4+3] += wv*tv[3];
    }
    wv = wn;
  }
  #pragma unroll
  for (int q = 0; q < 4; ++q){
    const f32x4 tv = swz_load4(tl, 127, w*4 + q);
    acc[q*4+0] += wv*tv[0]; acc[q*4+1] += wv*tv[1];
    acc[q*4+2] += wv*tv[2]; acc[q*4+3] += wv*tv[3];
  }
  // silu + per-thread j-sum
  f32x4 cs = {0,0,0,0};
  #pragma unroll
  for (int i = 0; i < 16; ++i){
    #pragma unroll
    for (int cc = 0; cc < 4; ++cc) cs[cc] += silu_f(acc[i][cc]);
  }
  *(f32x4*)&colsum[w][lane*4] = cs;
  __syncthreads();
  {
    const int c = tid;  // 0..255
    const float v = (colsum[0][c] + colsum[1][c] + colsum[2][c] + colsum[3][c])
                    * ws[OFF_Q + bi*256 + c];
    atomicAdd(&den40[(c>>5)*5 + cq], v);
  }
  __syncthreads();
  if (tid < 8) atomicAdd(&ws[OFF_DEN + bi*40 + tid*5 + cq], den40[tid*5 + cq]);
}

// ---------------------------------------------------------------- K5: MFMA ev/out2 + fp32 out1 + j-reductions
__global__ __launch_bounds__(512, 4) void k5_pass2(
    const float* __restrict__ x1, const float* __restrict__ x2,
    const float* __restrict__ r1, const float* __restrict__ r2,
    float* __restrict__ ws)
{
  __shared__ unsigned short tA[8192];     // [64 j][128 k] bf16, swizzled
  __shared__ unsigned short wevB[8192];   // [64 c][128 k] bf16, swizzled
  __shared__ unsigned short wcombB[8192]; // [128 d][64 hd] bf16, swizzled
  __shared__ unsigned short epB[4096];    // [64 j][64 hd] bf16, swizzled
  __shared__ float num[8][64];
  __shared__ float acc17[17*128];
  __shared__ float ql[256];
  __shared__ float rdenl[40];

  const int tid  = threadIdx.x;
  const int lane = tid & 63;
  const int w    = tid >> 6;
  const int wm   = w & 3;
  const int wn   = w >> 2;
  const int l15  = lane & 15;
  const int kq   = lane >> 4;

  const int bi = blockIdx.x >> 1;
  const int jh = blockIdx.x & 1;
  const int j0 = jh*64;
  const int b  = bi >> 7;

  #pragma unroll
  for (int p = 0; p < 4; ++p){
    const int idx = tid + p*512;
    const int j = idx >> 5;
    const int d4 = (idx & 31)*4;
    const float4 v = *(const float4*)&ws[OFF_T + (bi*128 + j0 + j)*128 + d4];
    uint2 u;
    u.x = packbf(v.x, v.y);
    u.y = packbf(v.z, v.w);
    *(uint2*)((char*)tA + j*256 + ((d4*2) ^ ((j&7)<<4))) = u;
  }
  if (tid < 64) *(float4*)&ql[tid*4] = *(const float4*)&ws[OFF_Q + bi*256 + tid*4];
  if (tid < 40) rdenl[tid] = 1.0f / ws[OFF_DEN + bi*40 + tid];
  for (int idx = tid; idx < 17*128; idx += 512) acc17[idx] = 0.f;
  __syncthreads();

  { // num[h][jl]
    const int hh = tid >> 6, jl = tid & 63;
    const float* krow = &ws[OFF_K + (b*128 + j0 + jl)*256 + hh*32];
    float a = 0.f;
    #pragma unroll
    for (int dh = 0; dh < 32; ++dh) a += ql[hh*32+dh]*krow[dh];
    num[hh][jl] = a;
  }

  const int jA = wm*16 + l15;
  bf16x8 af[4];
  #pragma unroll
  for (int ks = 0; ks < 4; ++ks)
    af[ks] = *(const bf16x8*)((const char*)tA + jA*256 + ((ks*64 + kq*16) ^ ((jA&7)<<4)));

  const uint4* wevt = (const uint4*)(ws + OFF_WEVT);
  const uint4* wct  = (const uint4*)(ws + OFF_WCT);

  for (int s = 0; s < 5; ++s){
    f32x4 o0 = {0,0,0,0}, o1 = {0,0,0,0}, o2 = {0,0,0,0}, o3 = {0,0,0,0};
    for (int ch4 = 0; ch4 < 4; ++ch4){
      __syncthreads();
      #pragma unroll
      for (int p = 0; p < 2; ++p){
        const int idx = tid + p*512;
        const int cl = idx & 63, kg = idx >> 6;
        const uint4 v = wevt[(s*256 + ch4*64 + cl)*16 + kg];
        *(uint4*)((char*)wevB + cl*256 + ((kg*16) ^ ((cl&7)<<4))) = v;
      }
      #pragma unroll
      for (int p = 0; p < 2; ++p){
        const int idx = tid + p*512;
        const int hg = idx & 7, d = idx >> 3;
        const uint4 v = wct[d*32 + ch4*8 + hg];
        *(uint4*)((char*)wcombB + d*128 + ((hg*16) ^ ((d&7)<<4))) = v;
      }
      __syncthreads();
      f32x4 ev0 = {0,0,0,0}, ev1 = {0,0,0,0};
      {
        const int c0l = wn*32 + l15;
        const int c1l = c0l + 16;
        #pragma unroll
        for (int ks = 0; ks < 4; ++ks){
          const bf16x8 b0 = *(const bf16x8*)((const char*)wevB + c0l*256 + ((ks*64 + kq*16) ^ ((c0l&7)<<4)));
          const bf16x8 b1 = *(const bf16x8*)((const char*)wevB + c1l*256 + ((ks*64 + kq*16) ^ ((c1l&7)<<4)));
          ev0 = __builtin_amdgcn_mfma_f32_16x16x32_bf16(af[ks], b0, ev0, 0, 0, 0);
          ev1 = __builtin_amdgcn_mfma_f32_16x16x32_bf16(af[ks], b1, ev1, 0, 0, 0);
        }
      }
      #pragma unroll
      for (int nt = 0; nt < 2; ++nt){
        const int cl = wn*32 + nt*16 + l15;
        const int cglob = s*256 + ch4*64 + cl;
        #pragma unroll
        for (int r = 0; r < 4; ++r){
          const int jl = wm*16 + kq*4 + r;
          const float pvv = ws[OFF_PV + (b*128 + j0 + jl)*1280 + cglob];
          const float evv = (nt == 0) ? ev0[r] : ev1[r];
          *(unsigned short*)((char*)epB + jl*128 + ((cl*2) ^ ((jl&7)<<4))) = f2bf(evv * pvv);
        }
      }
      __syncthreads();
      #pragma unroll
      for (int ks = 0; ks < 2; ++ks){
        const bf16x8 a = *(const bf16x8*)((const char*)epB + jA*128 + ((ks*64 + kq*16) ^ ((jA&7)<<4)));
        #pragma unroll
        for (int nt = 0; nt < 4; ++nt){
          const int dl = wn*64 + nt*16 + l15;
          const bf16x8 bb = *(const bf16x8*)((const char*)wcombB + dl*128 + ((ks*64 + kq*16) ^ ((dl&7)<<4)));
          if      (nt == 0) o0 = __builtin_amdgcn_mfma_f32_16x16x32_bf16(a, bb, o0, 0, 0, 0);
          else if (nt == 1) o1 = __builtin_amdgcn_mfma_f32_16x16x32_bf16(a, bb, o1, 0, 0, 0);
          else if (nt == 2) o2 = __builtin_amdgcn_mfma_f32_16x16x32_bf16(a, bb, o2, 0, 0, 0);
          else              o3 = __builtin_amdgcn_mfma_f32_16x16x32_bf16(a, bb, o3, 0, 0, 0);
        }
      }
    }
    #pragma unroll
    for (int r = 0; r < 4; ++r){
      const int jl = wm*16 + kq*4 + r;
      const float* vwbase = ws + OFF_VW + (b*128 + j0 + jl)*5120 + s*1024 + wn*64 + l15;
      #pragma unroll
      for (int hh = 0; hh < 8; ++hh){
        const float at = num[hh][jl] * rdenl[hh*5 + s];
        const float* vp = vwbase + hh*128;
        o0[r] += at * vp[0];
        o1[r] += at * vp[16];
        o2[r] += at * vp[32];
        o3[r] += at * vp[48];
      }
    }
    if (s == 0){
      #pragma unroll
      for (int nt = 0; nt < 4; ++nt){
        const f32x4 oo = (nt==0)?o0:(nt==1)?o1:(nt==2)?o2:o3;
        float p = oo[0] + oo[1] + oo[2] + oo[3];
        p += __shfl_xor(p, 16);
        p += __shfl_xor(p, 32);
        if (lane < 16) atomicAdd(&acc17[wn*64 + nt*16 + lane], p);
      }
    } else if (s <= 2){
      const int M = (s == 1) ? 3 : 5;
      const int slot0 = (s == 1) ? 1 : 4;
      const float* rw = (s == 1) ? r1 : r2;
      for (int m = 0; m < M; ++m){
        float wj[4];
        #pragma unroll
        for (int r = 0; r < 4; ++r)
          wj[r] = rw[(bi*128 + j0 + wm*16 + kq*4 + r)*M + m];
        #pragma unroll
        for (int nt = 0; nt < 4; ++nt){
          const f32x4 oo = (nt==0)?o0:(nt==1)?o1:(nt==2)?o2:o3;
          float p = wj[0]*oo[0] + wj[1]*oo[1] + wj[2]*oo[2] + wj[3]*oo[3];
          p += __shfl_xor(p, 16);
          p += __shfl_xor(p, 32);
          if (lane < 16) atomicAdd(&acc17[(slot0+m)*128 + wn*64 + nt*16 + lane], p);
        }
      }
    } else {
      const int M = (s == 3) ? 3 : 5;
      const int slot0 = (s == 3) ? 9 : 12;
      const float* xw = (s == 3) ? x1 : x2;
      for (int m = 0; m < M; ++m){
        #pragma unroll
        for (int nt = 0; nt < 4; ++nt){
          const int d = wn*64 + nt*16 + l15;
          const f32x4 oo = (nt==0)?o0:(nt==1)?o1:(nt==2)?o2:o3;
          float p = 0.f;
          #pragma unroll
          for (int r = 0; r < 4; ++r)
            p += xw[((b*128 + j0 + wm*16 + kq*4 + r)*128 + d)*M + m] * oo[r];
          p += __shfl_xor(p, 16);
          p += __shfl_xor(p, 32);
          if (lane < 16) atomicAdd(&acc17[(slot0+m)*128 + d], p);
        }
      }
    }
  }
  __syncthreads();
  for (int idx = tid; idx < 2176; idx += 512)
    ws[OFF_ACC + (bi*2 + jh)*2176 + idx] = acc17[idx];
}

// ---------------------------------------------------------------- K6: tail (one row per block)
__global__ __launch_bounds__(256) void k6_tail(
    const float* __restrict__ h,
    const float* __restrict__ P1, const float* __restrict__ P2,
    const float* __restrict__ Wf1a, const float* __restrict__ bf1a,
    const float* __restrict__ Wf2a, const float* __restrict__ bf2a,
    const float* __restrict__ Wf1b, const float* __restrict__ bf1b,
    const float* __restrict__ Wf2b, const float* __restrict__ bf2b,
    const float* __restrict__ ws, float* __restrict__ out)
{
  __shared__ float a17[2176];
  __shared__ float h2s[128];
  __shared__ float x1a[384], x2a[640];
  __shared__ float pj1[384], pj2[640];
  __shared__ float inv1[128], inv2[128];
  __shared__ float za[512], zb[512];
  __shared__ float m1a[128], m2a[128], m1b[128], m2b[128];
  const int tid = threadIdx.x;
  const int row = blockIdx.x;
  for (int idx = tid; idx < 2176; idx += 256)
    a17[idx] = ws[OFF_ACC + (row*2)*2176 + idx] + ws[OFF_ACC + (row*2+1)*2176 + idx];
  __syncthreads();
  if (tid < 128) h2s[tid] = h[row*128 + tid] + a17[tid];
  for (int idx = tid; idx < 384; idx += 256){
    const int d = idx/3, m = idx - d*3;
    x1a[idx] = a17[(1+m)*128 + d] + a17[(9+m)*128 + d];
  }
  for (int idx = tid; idx < 640; idx += 256){
    const int d = idx/5, m = idx - d*5;
    x2a[idx] = a17[(4+m)*128 + d] + a17[(12+m)*128 + d];
  }
  __syncthreads();
  if (tid < 128){
    const int e = tid;
    float pa[3] = {0.f,0.f,0.f};
    for (int d = 0; d < 128; ++d){
      const float p = P1[d*128 + e];
      pa[0] += x1a[d*3+0]*p;
      pa[1] += x1a[d*3+1]*p;
      pa[2] += x1a[d*3+2]*p;
    }
    pj1[e*3+0] = pa[0]; pj1[e*3+1] = pa[1]; pj1[e*3+2] = pa[2];
    inv1[e] = sqrtf(pa[0]*pa[0] + pa[1]*pa[1] + pa[2]*pa[2] + 1e-12f);
  } else {
    const int e = tid - 128;
    float pa[5] = {0.f,0.f,0.f,0.f,0.f};
    for (int d = 0; d < 128; ++d){
      const float p = P2[d*128 + e];
      pa[0] += x2a[d*5+0]*p;
      pa[1] += x2a[d*5+1]*p;
      pa[2] += x2a[d*5+2]*p;
      pa[3] += x2a[d*5+3]*p;
      pa[4] += x2a[d*5+4]*p;
    }
    #pragma unroll
    for (int m = 0; m < 5; ++m) pj2[e*5+m] = pa[m];
    inv2[e] = sqrtf(pa[0]*pa[0]+pa[1]*pa[1]+pa[2]*pa[2]+pa[3]*pa[3]+pa[4]*pa[4] + 1e-12f);
  }
  __syncthreads();
  for (int it = 0; it < 2; ++it){
    const int f = tid + it*256;
    float av = bf1a[f], bv_ = bf1b[f];
    #pragma unroll 4
    for (int k = 0; k < 128; ++k){
      av  += h2s[k]*Wf1a[k*512 + f];
      bv_ += h2s[k]*Wf1b[k*512 + f];
    }
    #pragma unroll 4
    for (int k = 0; k < 128; ++k){
      av  += inv1[k]*Wf1a[(128+k)*512 + f];
      bv_ += inv2[k]*Wf1b[(128+k)*512 + f];
    }
    za[f] = silu_f(av); zb[f] = silu_f(bv_);
  }
  __syncthreads();
  {
    const int g = tid;
    float am = bf2a[g], bm = bf2b[g];
    #pragma unroll 4
    for (int f = 0; f < 512; ++f){
      am += za[f]*Wf2a[f*256 + g];
      bm += zb[f]*Wf2b[f*256 + g];
    }
    if (g < 128){ m1a[g] = am; m1b[g] = bm; }
    else        { m2a[g-128] = am; m2b[g-128] = bm; }
  }
  __syncthreads();
  if (tid < 128){
    const int d = tid;
    const int ob = (row*128 + d)*9;
    out[ob+0] = h2s[d] + m1a[d] + m1b[d];
    #pragma unroll
    for (int m = 0; m < 3; ++m)
      out[ob+1+m] = x1a[d*3+m] + pj1[d*3+m]*m2a[d];
    #pragma unroll
    for (int m = 0; m < 5; ++m)
      out[ob+4+m] = x2a[d*5+m] + pj2[d*5+m]*m2b[d];
  }
}

// ----------------------------------------------------------------
extern "C" void kernel_launch(void* const* d_in, const int* in_sizes, int n_in,
                              void* d_out, int out_size, void* d_ws, size_t ws_size,
                              hipStream_t stream)
{
  (void)in_sizes; (void)n_in; (void)out_size; (void)ws_size;
  const float* h    = (const float*)d_in[0];
  const float* x1   = (const float*)d_in[1];
  const float* x2   = (const float*)d_in[2];
  const float* t_ij = (const float*)d_in[3];
  const float* r1   = (const float*)d_in[4];
  const float* r2   = (const float*)d_in[5];
  const float* g_i  = (const float*)d_in[6];
  const float* g_j  = (const float*)d_in[7];
  const float* Wq   = (const float*)d_in[8];
  const float* Wk   = (const float*)d_in[9];
  const float* Wv1  = (const float*)d_in[10];
  const float* bv1  = (const float*)d_in[11];
  const float* Wv2  = (const float*)d_in[12];
  const float* bv2  = (const float*)d_in[13];
  const float* Wp1  = (const float*)d_in[14];
  const float* bp1  = (const float*)d_in[15];
  const float* Wp2  = (const float*)d_in[16];
  const float* bp2  = (const float*)d_in[17];
  const float* Wek  = (const float*)d_in[18];
  const float* Wev  = (const float*)d_in[19];
  const float* Wcomb= (const float*)d_in[20];
  const float* Wqh  = (const float*)d_in[21];
  const float* Wk1h = (const float*)d_in[22];
  const float* Wk2h = (const float*)d_in[23];
  const float* Wep  = (const float*)d_in[24];
  const float* Wres = (const float*)d_in[25];
  const float* P1   = (const float*)d_in[26];
  const float* P2   = (const float*)d_in[27];
  const float* Wf1a = (const float*)d_in[28];
  const float* bf1a = (const float*)d_in[29];
  const float* Wf2a = (const float*)d_in[30];
  const float* bf2a = (const float*)d_in[31];
  const float* Wf1b = (const float*)d_in[32];
  const float* bf1b = (const float*)d_in[33];
  const float* Wf2b = (const float*)d_in[34];
  const float* bf2b = (const float*)d_in[35];
  float* ws  = (float*)d_ws;
  float* out = (float*)d_out;

  k0a_ln <<<dim3(256),  dim3(128), 0, stream>>>(h, g_i, g_j, ws);
  k0b_qkv<<<dim3(1536), dim3(256), 0, stream>>>(Wq, Wk, Wv1, bv1, Wp1, bp1, ws);
  k0c_qk12<<<dim3(256), dim3(256), 0, stream>>>(x1, x2, Wqh, Wk1h, Wk2h, ws);
  k1_vp  <<<dim3(320),  dim3(256), 0, stream>>>(Wv2, bv2, Wp2, bp2, ws);
  k2_vw  <<<dim3(256),  dim3(256), 0, stream>>>(Wcomb, ws);
  k_cvt  <<<dim3(88),   dim3(256), 0, stream>>>(Wev, Wcomb, ws);
  k3_t   <<<dim3(512),  dim3(512), 0, stream>>>(t_ij, Wep, Wres, ws);
  k4_den <<<dim3(2560), dim3(256), 0, stream>>>(Wek, ws);
  k5_pass2<<<dim3(512), dim3(512), 0, stream>>>(x1, x2, r1, r2, ws);
  k6_tail<<<dim3(256),  dim3(256), 0, stream>>>(h, P1, P2, Wf1a, bf1a, Wf2a, bf2a, Wf1b, bf1b, Wf2b, bf2b, ws, out);
}

// Round 7
// 702.127 us; speedup vs baseline: 2.4979x; 2.4979x over previous
//
#include <hip/hip_runtime.h>
#include <math.h>

// B=2 N=128 D=128 DE=64 H=8 DH=32 DI=256 DMI=512 S=5 SDI=1280 FFD=512
// Workspace offsets (float units):
#define OFF_Q    0         // (B*N,256)  hi@Wq
#define OFF_K    65536     // (B*N,256)  hj@Wk
#define OFF_A1V  131072    // (B*N,512)  silu(hj@Wv1+bv1)
#define OFF_A1P  262144    // (B*N,512)  silu(hj@Wp1+bp1)
#define OFF_V    393216    // (B*N,1280) a1v@Wv2+bv2
#define OFF_PV   720896    // (B*N,1280) a1p@Wp2+bp2
#define OFF_VW   1048576   // (B*N,5,8,128) v folded through Wcomb
#define OFF_QK   2359296   // (B*N,1024) [q1(192) q2(320) k1(192) k2(320)]
#define OFF_T    2621440   // (B,N,N,128) t
#define OFF_DEN  6815744   // (B*N,40)  den[h][s]
#define OFF_ACC  6825984   // (B*N,2,17,128) j-reduced partials
#define OFF_WEVT 7940096   // bf16 [1280 c][128 k] transposed Wev (81920 floats)
#define OFF_WCT  8022016   // bf16 [128 d][256 hd] transposed Wcomb (16384 floats)
#define OFF_HI   8038400   // (B*N,128) ln(h)*g_i
#define OFF_HJ   8071168   // (B*N,128) ln(h)*g_j
// total 8103936 floats = 32.4 MB

typedef __bf16 bf16x8 __attribute__((ext_vector_type(8)));
typedef float  f32x4  __attribute__((ext_vector_type(4)));

__device__ __forceinline__ float silu_f(float x){
  return x / (1.0f + __expf(-x));
}
__device__ __forceinline__ unsigned short f2bf(float x){
  union{float f; unsigned u;} c; c.f = x;
  unsigned r = c.u + 0x7FFFu + ((c.u >> 16) & 1u);
  return (unsigned short)(r >> 16);
}
__device__ __forceinline__ unsigned packbf(float a, float b){
  return (unsigned)f2bf(a) | ((unsigned)f2bf(b) << 16);
}
// swizzled fp32 LDS tile: row k (256B), 16B chunks XORed with (k>>2)&15
__device__ __forceinline__ void swz_store(float* Abase, int k, int j, float v){
  *(float*)((char*)Abase + k*256 + ((((j>>2) ^ ((k>>2)&15))) << 4) + ((j&3)<<2)) = v;
}
__device__ __forceinline__ f32x4 swz_load4(const float* Abase, int k, int chunk){
  return *(const f32x4*)((const char*)Abase + k*256 + ((chunk ^ ((k>>2)&15)) << 4));
}

// ---------------------------------------------------------------- K0a: LayerNorm (one row per block)
__global__ __launch_bounds__(128) void k0a_ln(
    const float* __restrict__ h, const float* __restrict__ g_i, const float* __restrict__ g_j,
    float* __restrict__ ws)
{
  __shared__ float red[2];
  const int r = blockIdx.x, tid = threadIdx.x;
  const int w = tid >> 6, l = tid & 63;
  const float hv = h[r*128 + tid];
  float s = hv;
  #pragma unroll
  for (int o = 1; o < 64; o <<= 1) s += __shfl_xor(s, o);
  if (l == 0) red[w] = s;
  __syncthreads();
  const float mu = (red[0] + red[1]) * (1.f/128.f);
  const float dv = hv - mu;
  float s2 = dv*dv;
  #pragma unroll
  for (int o = 1; o < 64; o <<= 1) s2 += __shfl_xor(s2, o);
  __syncthreads();
  if (l == 0) red[w] = s2;
  __syncthreads();
  const float rstd = 1.0f / sqrtf((red[0] + red[1])*(1.f/128.f) + 1e-5f);
  ws[OFF_HI + r*128 + tid] = dv * rstd * g_i[tid];
  ws[OFF_HJ + r*128 + tid] = dv * rstd * g_j[tid];
  if (tid < 40) ws[OFF_DEN + r*40 + tid] = 0.f;  // zero for k4 atomics
}

// ---------------------------------------------------------------- K0b: q/k/a1v/a1p (element-parallel GEMM)
__global__ __launch_bounds__(256) void k0b_qkv(
    const float* __restrict__ Wq, const float* __restrict__ Wk,
    const float* __restrict__ Wv1, const float* __restrict__ bv1,
    const float* __restrict__ Wp1, const float* __restrict__ bp1,
    float* __restrict__ ws)
{
  __shared__ float hrow[128];
  const int bid = blockIdx.x;
  const int row = bid / 6, ch = bid - 6*(bid/6);
  const int tid = threadIdx.x;
  if (tid < 128) hrow[tid] = ws[((ch == 0) ? OFF_HI : OFF_HJ) + row*128 + tid];
  __syncthreads();
  const float* W; int c; float bias = 0.f; bool act = false; float* dst; int wstride;
  switch(ch){
    case 0: W = Wq;  c = tid;      wstride = 256; dst = ws + OFF_Q   + row*256 + c; break;
    case 1: W = Wk;  c = tid;      wstride = 256; dst = ws + OFF_K   + row*256 + c; break;
    case 2: W = Wv1; c = tid;      wstride = 512; bias = bv1[c]; act = true; dst = ws + OFF_A1V + row*512 + c; break;
    case 3: W = Wv1; c = 256+tid;  wstride = 512; bias = bv1[c]; act = true; dst = ws + OFF_A1V + row*512 + c; break;
    case 4: W = Wp1; c = tid;      wstride = 512; bias = bp1[c]; act = true; dst = ws + OFF_A1P + row*512 + c; break;
    default:W = Wp1; c = 256+tid;  wstride = 512; bias = bp1[c]; act = true; dst = ws + OFF_A1P + row*512 + c; break;
  }
  float acc = bias;
  #pragma unroll 8
  for (int d = 0; d < 128; ++d) acc += hrow[d] * W[d*wstride + c];
  *dst = act ? silu_f(acc) : acc;
}

// ---------------------------------------------------------------- K0c: q1/q2/k1/k2 (one row per block)
__global__ __launch_bounds__(256) void k0c_qk12(
    const float* __restrict__ x1, const float* __restrict__ x2,
    const float* __restrict__ Wqh, const float* __restrict__ Wk1h, const float* __restrict__ Wk2h,
    float* __restrict__ ws)
{
  __shared__ float x1r[384], x2r[640];
  const int row = blockIdx.x, tid = threadIdx.x;
  for (int idx = tid; idx < 384; idx += 256) x1r[idx] = x1[row*384 + idx];
  for (int idx = tid; idx < 640; idx += 256) x2r[idx] = x2[row*640 + idx];
  __syncthreads();
  for (int idx = tid; idx < 512; idx += 256){
    if (idx < 192){
      const int e = idx/3, m = idx - e*3;
      float qa = 0.f, ka = 0.f;
      #pragma unroll 8
      for (int d = 0; d < 128; ++d){
        const float xv = x1r[d*3 + m];
        qa += xv*Wqh[d*64 + e];
        ka += xv*Wk1h[d*64 + e];
      }
      ws[OFF_QK + row*1024 + idx] = qa;
      ws[OFF_QK + row*1024 + 512 + idx] = ka;
    } else {
      const int i2 = idx - 192;
      const int e = i2/5, m = i2 - e*5;
      float qa = 0.f, ka = 0.f;
      #pragma unroll 8
      for (int d = 0; d < 128; ++d){
        const float xv = x2r[d*5 + m];
        qa += xv*Wqh[d*64 + e];
        ka += xv*Wk2h[d*64 + e];
      }
      ws[OFF_QK + row*1024 + 192 + i2] = qa;
      ws[OFF_QK + row*1024 + 704 + i2] = ka;
    }
  }
}

// ---------------------------------------------------------------- K1: v/pv GEMM (M=512,N=1280,K=512)
__global__ __launch_bounds__(256) void k1_vp(
    const float* __restrict__ Wv2, const float* __restrict__ bv2,
    const float* __restrict__ Wp2, const float* __restrict__ bp2,
    float* __restrict__ ws)
{
  __shared__ float A[512][16];   // K x rowtile (transposed)
  __shared__ float Bc[64][128];  // K-chunk x coltile
  const int tid = threadIdx.x;
  const int rt = blockIdx.x & 31;
  const int ct = blockIdx.x >> 5;
  const int r0 = rt*16;
  const bool isP = (r0 >= 256);
  const int rbase = isP ? (r0 - 256) : r0;
  const float* __restrict__ src  = ws + (isP ? OFF_A1P : OFF_A1V);
  const float* __restrict__ W    = isP ? Wp2 : Wv2;
  const float* __restrict__ bias = isP ? bp2 : bv2;
  const int c0 = ct*128;
  for (int idx = tid; idx < 2048; idx += 256){
    const int rl = idx & 15;
    const int c4 = (idx >> 4) * 4;
    const float4 v = *(const float4*)&src[(rbase+rl)*512 + c4];
    A[c4+0][rl] = v.x; A[c4+1][rl] = v.y; A[c4+2][rl] = v.z; A[c4+3][rl] = v.w;
  }
  float acc[4][2] = {{0.f}};
  const int rg = tid & 3;
  const int cg = tid >> 2;
  for (int kc = 0; kc < 8; ++kc){
    __syncthreads();
    for (int idx = tid; idx < 2048; idx += 256){
      const int kl = idx >> 5;
      const int c4 = (idx & 31)*4;
      *(float4*)&Bc[kl][c4] = *(const float4*)&W[(kc*64+kl)*1280 + c0 + c4];
    }
    __syncthreads();
    #pragma unroll 8
    for (int k = 0; k < 64; ++k){
      const float4 a = *(const float4*)&A[kc*64+k][rg*4];
      const float b0 = Bc[k][cg*2], b1 = Bc[k][cg*2+1];
      acc[0][0] += a.x*b0; acc[0][1] += a.x*b1;
      acc[1][0] += a.y*b0; acc[1][1] += a.y*b1;
      acc[2][0] += a.z*b0; acc[2][1] += a.z*b1;
      acc[3][0] += a.w*b0; acc[3][1] += a.w*b1;
    }
  }
  float* __restrict__ dst = ws + (isP ? OFF_PV : OFF_V);
  for (int rr = 0; rr < 4; ++rr)
    for (int cc = 0; cc < 2; ++cc){
      const int c = c0 + cg*2 + cc;
      dst[(rbase + rg*4 + rr)*1280 + c] = acc[rr][cc] + bias[c];
    }
}

// ---------------------------------------------------------------- K2: vW = fold v through Wcomb (one j per block)
__global__ __launch_bounds__(256) void k2_vw(const float* __restrict__ Wcomb, float* __restrict__ ws)
{
  __shared__ float vr[1280];
  const int j = blockIdx.x, tid = threadIdx.x;
  for (int idx = tid; idx < 320; idx += 256)
    *(float4*)&vr[idx*4] = *(const float4*)&ws[OFF_V + j*1280 + idx*4];
  __syncthreads();
  const int d = tid & 127;
  for (int sh = tid >> 7; sh < 40; sh += 2){
    const int s = sh >> 3, hh = sh & 7;
    float a = 0.f;
    #pragma unroll 8
    for (int dh = 0; dh < 32; ++dh)
      a += vr[s*256 + hh*32 + dh] * Wcomb[(hh*32+dh)*128 + d];
    ws[OFF_VW + j*5120 + sh*128 + d] = a;
  }
}

// ---------------------------------------------------------------- K2b: transpose-convert Wev/Wcomb to bf16
__global__ __launch_bounds__(256) void k_cvt(
    const float* __restrict__ Wev, const float* __restrict__ Wcomb, float* __restrict__ ws)
{
  __shared__ float ld[16][256];
  const int tid = threadIdx.x;
  if (blockIdx.x < 80){
    const int c0 = blockIdx.x*16;
    for (int p = 0; p < 8; ++p){
      const int idx = tid + p*256;
      const int k = idx >> 4, cl = idx & 15;
      ld[cl][k] = Wev[k*1280 + c0 + cl];
    }
    __syncthreads();
    const int cl = tid >> 4, k8 = tid & 15;
    uint4 u;
    u.x = packbf(ld[cl][k8*8+0], ld[cl][k8*8+1]);
    u.y = packbf(ld[cl][k8*8+2], ld[cl][k8*8+3]);
    u.z = packbf(ld[cl][k8*8+4], ld[cl][k8*8+5]);
    u.w = packbf(ld[cl][k8*8+6], ld[cl][k8*8+7]);
    ((uint4*)(ws + OFF_WEVT))[(c0+cl)*16 + k8] = u;
  } else {
    const int c0 = (blockIdx.x - 80)*16;
    for (int p = 0; p < 16; ++p){
      const int idx = tid + p*256;
      const int k = idx >> 4, cl = idx & 15;
      ld[cl][k] = Wcomb[k*128 + c0 + cl];
    }
    __syncthreads();
    const int cl = tid >> 4, k8i = tid & 15;
    for (int pass = 0; pass < 2; ++pass){
      const int k8 = k8i + pass*16;
      uint4 u;
      u.x = packbf(ld[cl][k8*8+0], ld[cl][k8*8+1]);
      u.y = packbf(ld[cl][k8*8+2], ld[cl][k8*8+3]);
      u.z = packbf(ld[cl][k8*8+4], ld[cl][k8*8+5]);
      u.w = packbf(ld[cl][k8*8+6], ld[cl][k8*8+7]);
      ((uint4*)(ws + OFF_WCT))[(c0+cl)*32 + k8] = u;
    }
  }
}

// ---------------------------------------------------------------- K3: t = w_ij@Wep + t_ij@Wres (fp32, streamed W)
// grid (bi,jh)=512 blocks x 512 thr. A[256k][64j] swizzled LDS; W read direct from global.
// Phase 1: w_ij -> A rows 0..127 (kst scratch aliases A rows 128..255).
// Phase 2: t_ij -> A rows 128..255. Then GEMM.
__global__ __launch_bounds__(512, 2) void k3_t(
    const float* __restrict__ t_ij, const float* __restrict__ Wep, const float* __restrict__ Wres,
    float* __restrict__ ws)
{
  __shared__ float A[16384];     // 64KB: [256 k][64 j] swizzled
  __shared__ float qrow[512];
  float* kst = A + 8192;         // 32KB flat scratch (rows 128..255 region) during phase 1
  const int tid = threadIdx.x;
  const int bi = blockIdx.x >> 1;
  const int jt = blockIdx.x & 1;
  const int j0 = jt*64;
  const int b  = bi >> 7;
  if (tid < 128) *(float4*)&qrow[tid*4] = *(const float4*)&ws[OFF_QK + bi*1024 + tid*4];
  // ---- phase 1: w_ij ----
  for (int jq = 0; jq < 4; ++jq){
    __syncthreads();
    for (int idx = tid; idx < 2048; idx += 512){   // stage 16 k-rows transposed (8192 floats)
      const int jl = idx & 15;
      const int c4 = (idx >> 4)*4;
      const float4 v = *(const float4*)&ws[OFF_QK + (b*128 + j0 + jq*16 + jl)*1024 + 512 + c4];
      kst[(c4+0)*16 + jl] = v.x; kst[(c4+1)*16 + jl] = v.y;
      kst[(c4+2)*16 + jl] = v.z; kst[(c4+3)*16 + jl] = v.w;
    }
    __syncthreads();
    for (int idx = tid; idx < 2048; idx += 512){   // w_ij[e][j] -> A rows 0..127
      const int jl = idx & 15;
      const int e  = idx >> 4;
      float acc = 0.f;
      if (e < 64){
        #pragma unroll
        for (int m = 0; m < 3; ++m) acc += qrow[e*3+m] * kst[(e*3+m)*16 + jl];
      } else {
        const int e2 = e - 64;
        #pragma unroll
        for (int m = 0; m < 5; ++m) acc += qrow[192 + e2*5+m] * kst[(192 + e2*5+m)*16 + jl];
      }
      swz_store(A, e, jq*16 + jl, acc);
    }
  }
  __syncthreads();
  // ---- phase 2: t_ij -> A rows 128..255 (transposed, swizzled) ----
  for (int idx = tid; idx < 2048; idx += 512){
    const int jl = idx >> 5;
    const int d4 = (idx & 31)*4;
    const float4 v = *(const float4*)&t_ij[(bi*128 + j0 + jl)*128 + d4];
    swz_store(A, 128+d4+0, jl, v.x);
    swz_store(A, 128+d4+1, jl, v.y);
    swz_store(A, 128+d4+2, jl, v.z);
    swz_store(A, 128+d4+3, jl, v.w);
  }
  __syncthreads();
  // main GEMM: 64j x 128c, per-thread 4j x 4c
  const int jg = tid >> 5;        // 0..15, j = jg*4+jj
  const int cg = tid & 31;        // c = cg*4
  f32x4 acc[4] = {{0,0,0,0},{0,0,0,0},{0,0,0,0},{0,0,0,0}};
  {
    const float* Wp = Wep + cg*4;
    f32x4 wv = *(const f32x4*)Wp;
    for (int k = 0; k < 127; ++k){
      const f32x4 wn = *(const f32x4*)(Wp + (k+1)*128);
      const f32x4 av = swz_load4(A, k, jg);
      acc[0] += wv*av[0]; acc[1] += wv*av[1]; acc[2] += wv*av[2]; acc[3] += wv*av[3];
      wv = wn;
    }
    const f32x4 av = swz_load4(A, 127, jg);
    acc[0] += wv*av[0]; acc[1] += wv*av[1]; acc[2] += wv*av[2]; acc[3] += wv*av[3];
  }
  {
    const float* Wp = Wres + cg*4;
    f32x4 wv = *(const f32x4*)Wp;
    for (int k = 0; k < 127; ++k){
      const f32x4 wn = *(const f32x4*)(Wp + (k+1)*128);
      const f32x4 av = swz_load4(A, 128+k, jg);
      acc[0] += wv*av[0]; acc[1] += wv*av[1]; acc[2] += wv*av[2]; acc[3] += wv*av[3];
      wv = wn;
    }
    const f32x4 av = swz_load4(A, 255, jg);
    acc[0] += wv*av[0]; acc[1] += wv*av[1]; acc[2] += wv*av[2]; acc[3] += wv*av[3];
  }
  #pragma unroll
  for (int jj = 0; jj < 4; ++jj)
    *(f32x4*)&ws[OFF_T + (bi*128 + j0 + jg*4 + jj)*128 + cg*4] = acc[jj];
}

// ---------------------------------------------------------------- K4: den (fp32, streamed Wek, no spill)
// grid 5120 = 256 bi x 2 jh x 10 cq(128 cols); block 256 thr; per-thread 8j x 4c (32 regs).
__global__ __launch_bounds__(256) void k4_den(
    const float* __restrict__ Wek, float* __restrict__ ws)
{
  __shared__ float tl[8192];        // 32KB [128 k][64 j] swizzled
  __shared__ float colsum[8][128];  // 4KB
  __shared__ float den40[40];
  const int tid = threadIdx.x;
  const int bid = blockIdx.x;
  const int bi = bid / 20;
  const int rem = bid - bi*20;
  const int jh = rem & 1;
  const int cq = rem >> 1;          // 0..9: 128-col chunk
  const int j0 = jh*64;
  // stage t tile (transposed, swizzled)
  for (int idx = tid; idx < 2048; idx += 256){
    const int j = idx >> 5;
    const int d4 = (idx & 31)*4;
    const float4 v = *(const float4*)&ws[OFF_T + (bi*128 + j0 + j)*128 + d4];
    swz_store(tl, d4+0, j, v.x);
    swz_store(tl, d4+1, j, v.y);
    swz_store(tl, d4+2, j, v.z);
    swz_store(tl, d4+3, j, v.w);
  }
  if (tid < 40) den40[tid] = 0.f;
  __syncthreads();
  const int w = tid >> 5;           // 0..7: j-rows w*8..w*8+7
  const int lane = tid & 31;        // c = lane*4 (128 cols per block)
  const float* wekp = Wek + cq*128 + lane*4;
  f32x4 acc[8];
  #pragma unroll
  for (int i = 0; i < 8; ++i) acc[i] = (f32x4){0,0,0,0};
  f32x4 wv = *(const f32x4*)wekp;
  for (int k = 0; k < 127; ++k){
    const f32x4 wn = *(const f32x4*)(wekp + (k+1)*1280);
    #pragma unroll
    for (int q = 0; q < 2; ++q){
      const f32x4 tv = swz_load4(tl, k, w*2 + q);   // broadcast across 32 lanes
      acc[q*4+0] += wv*tv[0]; acc[q*4+1] += wv*tv[1];
      acc[q*4+2] += wv*tv[2]; acc[q*4+3] += wv*tv[3];
    }
    wv = wn;
  }
  #pragma unroll
  for (int q = 0; q < 2; ++q){
    const f32x4 tv = swz_load4(tl, 127, w*2 + q);
    acc[q*4+0] += wv*tv[0]; acc[q*4+1] += wv*tv[1];
    acc[q*4+2] += wv*tv[2]; acc[q*4+3] += wv*tv[3];
  }
  // silu + per-thread j-sum
  f32x4 cs = {0,0,0,0};
  #pragma unroll
  for (int i = 0; i < 8; ++i){
    #pragma unroll
    for (int cc = 0; cc < 4; ++cc) cs[cc] += silu_f(acc[i][cc]);
  }
  *(f32x4*)&colsum[w][lane*4] = cs;
  __syncthreads();
  if (tid < 128){
    const int c = tid;
    const float jsum = colsum[0][c] + colsum[1][c] + colsum[2][c] + colsum[3][c]
                     + colsum[4][c] + colsum[5][c] + colsum[6][c] + colsum[7][c];
    const int col = cq*128 + c;        // 0..1279
    const int s  = col >> 8;
    const int hd = col & 255;
    atomicAdd(&den40[(hd>>5)*5 + s], jsum * ws[OFF_Q + bi*256 + hd]);
  }
  __syncthreads();
  if (tid < 40 && den40[tid] != 0.f)
    atomicAdd(&ws[OFF_DEN + bi*40 + tid], den40[tid]);
}

// ---------------------------------------------------------------- K5: MFMA ev/out2 + fp32 out1 + j-reductions
__global__ __launch_bounds__(512, 4) void k5_pass2(
    const float* __restrict__ x1, const float* __restrict__ x2,
    const float* __restrict__ r1, const float* __restrict__ r2,
    float* __restrict__ ws)
{
  __shared__ unsigned short tA[8192];     // [64 j][128 k] bf16, swizzled
  __shared__ unsigned short wevB[8192];   // [64 c][128 k] bf16, swizzled
  __shared__ unsigned short wcombB[8192]; // [128 d][64 hd] bf16, swizzled
  __shared__ unsigned short epB[4096];    // [64 j][64 hd] bf16, swizzled
  __shared__ float num[8][64];
  __shared__ float acc17[17*128];
  __shared__ float ql[256];
  __shared__ float rdenl[40];

  const int tid  = threadIdx.x;
  const int lane = tid & 63;
  const int w    = tid >> 6;
  const int wm   = w & 3;
  const int wn   = w >> 2;
  const int l15  = lane & 15;
  const int kq   = lane >> 4;

  const int bi = blockIdx.x >> 1;
  const int jh = blockIdx.x & 1;
  const int j0 = jh*64;
  const int b  = bi >> 7;

  #pragma unroll
  for (int p = 0; p < 4; ++p){
    const int idx = tid + p*512;
    const int j = idx >> 5;
    const int d4 = (idx & 31)*4;
    const float4 v = *(const float4*)&ws[OFF_T + (bi*128 + j0 + j)*128 + d4];
    uint2 u;
    u.x = packbf(v.x, v.y);
    u.y = packbf(v.z, v.w);
    *(uint2*)((char*)tA + j*256 + ((d4*2) ^ ((j&7)<<4))) = u;
  }
  if (tid < 64) *(float4*)&ql[tid*4] = *(const float4*)&ws[OFF_Q + bi*256 + tid*4];
  if (tid < 40) rdenl[tid] = 1.0f / ws[OFF_DEN + bi*40 + tid];
  for (int idx = tid; idx < 17*128; idx += 512) acc17[idx] = 0.f;
  __syncthreads();

  { // num[h][jl]
    const int hh = tid >> 6, jl = tid & 63;
    const float* krow = &ws[OFF_K + (b*128 + j0 + jl)*256 + hh*32];
    float a = 0.f;
    #pragma unroll
    for (int dh = 0; dh < 32; ++dh) a += ql[hh*32+dh]*krow[dh];
    num[hh][jl] = a;
  }

  const int jA = wm*16 + l15;
  bf16x8 af[4];
  #pragma unroll
  for (int ks = 0; ks < 4; ++ks)
    af[ks] = *(const bf16x8*)((const char*)tA + jA*256 + ((ks*64 + kq*16) ^ ((jA&7)<<4)));

  const uint4* wevt = (const uint4*)(ws + OFF_WEVT);
  const uint4* wct  = (const uint4*)(ws + OFF_WCT);

  for (int s = 0; s < 5; ++s){
    f32x4 o0 = {0,0,0,0}, o1 = {0,0,0,0}, o2 = {0,0,0,0}, o3 = {0,0,0,0};
    for (int ch4 = 0; ch4 < 4; ++ch4){
      __syncthreads();
      #pragma unroll
      for (int p = 0; p < 2; ++p){
        const int idx = tid + p*512;
        const int cl = idx & 63, kg = idx >> 6;
        const uint4 v = wevt[(s*256 + ch4*64 + cl)*16 + kg];
        *(uint4*)((char*)wevB + cl*256 + ((kg*16) ^ ((cl&7)<<4))) = v;
      }
      #pragma unroll
      for (int p = 0; p < 2; ++p){
        const int idx = tid + p*512;
        const int hg = idx & 7, d = idx >> 3;
        const uint4 v = wct[d*32 + ch4*8 + hg];
        *(uint4*)((char*)wcombB + d*128 + ((hg*16) ^ ((d&7)<<4))) = v;
      }
      __syncthreads();
      f32x4 ev0 = {0,0,0,0}, ev1 = {0,0,0,0};
      {
        const int c0l = wn*32 + l15;
        const int c1l = c0l + 16;
        #pragma unroll
        for (int ks = 0; ks < 4; ++ks){
          const bf16x8 b0 = *(const bf16x8*)((const char*)wevB + c0l*256 + ((ks*64 + kq*16) ^ ((c0l&7)<<4)));
          const bf16x8 b1 = *(const bf16x8*)((const char*)wevB + c1l*256 + ((ks*64 + kq*16) ^ ((c1l&7)<<4)));
          ev0 = __builtin_amdgcn_mfma_f32_16x16x32_bf16(af[ks], b0, ev0, 0, 0, 0);
          ev1 = __builtin_amdgcn_mfma_f32_16x16x32_bf16(af[ks], b1, ev1, 0, 0, 0);
        }
      }
      #pragma unroll
      for (int nt = 0; nt < 2; ++nt){
        const int cl = wn*32 + nt*16 + l15;
        const int cglob = s*256 + ch4*64 + cl;
        #pragma unroll
        for (int r = 0; r < 4; ++r){
          const int jl = wm*16 + kq*4 + r;
          const float pvv = ws[OFF_PV + (b*128 + j0 + jl)*1280 + cglob];
          const float evv = (nt == 0) ? ev0[r] : ev1[r];
          *(unsigned short*)((char*)epB + jl*128 + ((cl*2) ^ ((jl&7)<<4))) = f2bf(evv * pvv);
        }
      }
      __syncthreads();
      #pragma unroll
      for (int ks = 0; ks < 2; ++ks){
        const bf16x8 a = *(const bf16x8*)((const char*)epB + jA*128 + ((ks*64 + kq*16) ^ ((jA&7)<<4)));
        #pragma unroll
        for (int nt = 0; nt < 4; ++nt){
          const int dl = wn*64 + nt*16 + l15;
          const bf16x8 bb = *(const bf16x8*)((const char*)wcombB + dl*128 + ((ks*64 + kq*16) ^ ((dl&7)<<4)));
          if      (nt == 0) o0 = __builtin_amdgcn_mfma_f32_16x16x32_bf16(a, bb, o0, 0, 0, 0);
          else if (nt == 1) o1 = __builtin_amdgcn_mfma_f32_16x16x32_bf16(a, bb, o1, 0, 0, 0);
          else if (nt == 2) o2 = __builtin_amdgcn_mfma_f32_16x16x32_bf16(a, bb, o2, 0, 0, 0);
          else              o3 = __builtin_amdgcn_mfma_f32_16x16x32_bf16(a, bb, o3, 0, 0, 0);
        }
      }
    }
    #pragma unroll
    for (int r = 0; r < 4; ++r){
      const int jl = wm*16 + kq*4 + r;
      const float* vwbase = ws + OFF_VW + (b*128 + j0 + jl)*5120 + s*1024 + wn*64 + l15;
      #pragma unroll
      for (int hh = 0; hh < 8; ++hh){
        const float at = num[hh][jl] * rdenl[hh*5 + s];
        const float* vp = vwbase + hh*128;
        o0[r] += at * vp[0];
        o1[r] += at * vp[16];
        o2[r] += at * vp[32];
        o3[r] += at * vp[48];
      }
    }
    if (s == 0){
      #pragma unroll
      for (int nt = 0; nt < 4; ++nt){
        const f32x4 oo = (nt==0)?o0:(nt==1)?o1:(nt==2)?o2:o3;
        float p = oo[0] + oo[1] + oo[2] + oo[3];
        p += __shfl_xor(p, 16);
        p += __shfl_xor(p, 32);
        if (lane < 16) atomicAdd(&acc17[wn*64 + nt*16 + lane], p);
      }
    } else if (s <= 2){
      const int M = (s == 1) ? 3 : 5;
      const int slot0 = (s == 1) ? 1 : 4;
      const float* rw = (s == 1) ? r1 : r2;
      for (int m = 0; m < M; ++m){
        float wj[4];
        #pragma unroll
        for (int r = 0; r < 4; ++r)
          wj[r] = rw[(bi*128 + j0 + wm*16 + kq*4 + r)*M + m];
        #pragma unroll
        for (int nt = 0; nt < 4; ++nt){
          const f32x4 oo = (nt==0)?o0:(nt==1)?o1:(nt==2)?o2:o3;
          float p = wj[0]*oo[0] + wj[1]*oo[1] + wj[2]*oo[2] + wj[3]*oo[3];
          p += __shfl_xor(p, 16);
          p += __shfl_xor(p, 32);
          if (lane < 16) atomicAdd(&acc17[(slot0+m)*128 + wn*64 + nt*16 + lane], p);
        }
      }
    } else {
      const int M = (s == 3) ? 3 : 5;
      const int slot0 = (s == 3) ? 9 : 12;
      const float* xw = (s == 3) ? x1 : x2;
      for (int m = 0; m < M; ++m){
        #pragma unroll
        for (int nt = 0; nt < 4; ++nt){
          const int d = wn*64 + nt*16 + l15;
          const f32x4 oo = (nt==0)?o0:(nt==1)?o1:(nt==2)?o2:o3;
          float p = 0.f;
          #pragma unroll
          for (int r = 0; r < 4; ++r)
            p += xw[((b*128 + j0 + wm*16 + kq*4 + r)*128 + d)*M + m] * oo[r];
          p += __shfl_xor(p, 16);
          p += __shfl_xor(p, 32);
          if (lane < 16) atomicAdd(&acc17[(slot0+m)*128 + d], p);
        }
      }
    }
  }
  __syncthreads();
  for (int idx = tid; idx < 2176; idx += 512)
    ws[OFF_ACC + (bi*2 + jh)*2176 + idx] = acc17[idx];
}

// ---------------------------------------------------------------- K6: tail (one row per block)
__global__ __launch_bounds__(256) void k6_tail(
    const float* __restrict__ h,
    const float* __restrict__ P1, const float* __restrict__ P2,
    const float* __restrict__ Wf1a, const float* __restrict__ bf1a,
    const float* __restrict__ Wf2a, const float* __restrict__ bf2a,
    const float* __restrict__ Wf1b, const float* __restrict__ bf1b,
    const float* __restrict__ Wf2b, const float* __restrict__ bf2b,
    const float* __restrict__ ws, float* __restrict__ out)
{
  __shared__ float a17[2176];
  __shared__ float h2s[128];
  __shared__ float x1a[384], x2a[640];
  __shared__ float pj1[384], pj2[640];
  __shared__ float inv1[128], inv2[128];
  __shared__ float za[512], zb[512];
  __shared__ float m1a[128], m2a[128], m1b[128], m2b[128];
  const int tid = threadIdx.x;
  const int row = blockIdx.x;
  for (int idx = tid; idx < 2176; idx += 256)
    a17[idx] = ws[OFF_ACC + (row*2)*2176 + idx] + ws[OFF_ACC + (row*2+1)*2176 + idx];
  __syncthreads();
  if (tid < 128) h2s[tid] = h[row*128 + tid] + a17[tid];
  for (int idx = tid; idx < 384; idx += 256){
    const int d = idx/3, m = idx - d*3;
    x1a[idx] = a17[(1+m)*128 + d] + a17[(9+m)*128 + d];
  }
  for (int idx = tid; idx < 640; idx += 256){
    const int d = idx/5, m = idx - d*5;
    x2a[idx] = a17[(4+m)*128 + d] + a17[(12+m)*128 + d];
  }
  __syncthreads();
  if (tid < 128){
    const int e = tid;
    float pa[3] = {0.f,0.f,0.f};
    for (int d = 0; d < 128; ++d){
      const float p = P1[d*128 + e];
      pa[0] += x1a[d*3+0]*p;
      pa[1] += x1a[d*3+1]*p;
      pa[2] += x1a[d*3+2]*p;
    }
    pj1[e*3+0] = pa[0]; pj1[e*3+1] = pa[1]; pj1[e*3+2] = pa[2];
    inv1[e] = sqrtf(pa[0]*pa[0] + pa[1]*pa[1] + pa[2]*pa[2] + 1e-12f);
  } else {
    const int e = tid - 128;
    float pa[5] = {0.f,0.f,0.f,0.f,0.f};
    for (int d = 0; d < 128; ++d){
      const float p = P2[d*128 + e];
      pa[0] += x2a[d*5+0]*p;
      pa[1] += x2a[d*5+1]*p;
      pa[2] += x2a[d*5+2]*p;
      pa[3] += x2a[d*5+3]*p;
      pa[4] += x2a[d*5+4]*p;
    }
    #pragma unroll
    for (int m = 0; m < 5; ++m) pj2[e*5+m] = pa[m];
    inv2[e] = sqrtf(pa[0]*pa[0]+pa[1]*pa[1]+pa[2]*pa[2]+pa[3]*pa[3]+pa[4]*pa[4] + 1e-12f);
  }
  __syncthreads();
  for (int it = 0; it < 2; ++it){
    const int f = tid + it*256;
    float av = bf1a[f], bv_ = bf1b[f];
    #pragma unroll 4
    for (int k = 0; k < 128; ++k){
      av  += h2s[k]*Wf1a[k*512 + f];
      bv_ += h2s[k]*Wf1b[k*512 + f];
    }
    #pragma unroll 4
    for (int k = 0; k < 128; ++k){
      av  += inv1[k]*Wf1a[(128+k)*512 + f];
      bv_ += inv2[k]*Wf1b[(128+k)*512 + f];
    }
    za[f] = silu_f(av); zb[f] = silu_f(bv_);
  }
  __syncthreads();
  {
    const int g = tid;
    float am = bf2a[g], bm = bf2b[g];
    #pragma unroll 4
    for (int f = 0; f < 512; ++f){
      am += za[f]*Wf2a[f*256 + g];
      bm += zb[f]*Wf2b[f*256 + g];
    }
    if (g < 128){ m1a[g] = am; m1b[g] = bm; }
    else        { m2a[g-128] = am; m2b[g-128] = bm; }
  }
  __syncthreads();
  if (tid < 128){
    const int d = tid;
    const int ob = (row*128 + d)*9;
    out[ob+0] = h2s[d] + m1a[d] + m1b[d];
    #pragma unroll
    for (int m = 0; m < 3; ++m)
      out[ob+1+m] = x1a[d*3+m] + pj1[d*3+m]*m2a[d];
    #pragma unroll
    for (int m = 0; m < 5; ++m)
      out[ob+4+m] = x2a[d*5+m] + pj2[d*5+m]*m2b[d];
  }
}

// ----------------------------------------------------------------
extern "C" void kernel_launch(void* const* d_in, const int* in_sizes, int n_in,
                              void* d_out, int out_size, void* d_ws, size_t ws_size,
                              hipStream_t stream)
{
  (void)in_sizes; (void)n_in; (void)out_size; (void)ws_size;
  const float* h    = (const float*)d_in[0];
  const float* x1   = (const float*)d_in[1];
  const float* x2   = (const float*)d_in[2];
  const float* t_ij = (const float*)d_in[3];
  const float* r1   = (const float*)d_in[4];
  const float* r2   = (const float*)d_in[5];
  const float* g_i  = (const float*)d_in[6];
  const float* g_j  = (const float*)d_in[7];
  const float* Wq   = (const float*)d_in[8];
  const float* Wk   = (const float*)d_in[9];
  const float* Wv1  = (const float*)d_in[10];
  const float* bv1  = (const float*)d_in[11];
  const float* Wv2  = (const float*)d_in[12];
  const float* bv2  = (const float*)d_in[13];
  const float* Wp1  = (const float*)d_in[14];
  const float* bp1  = (const float*)d_in[15];
  const float* Wp2  = (const float*)d_in[16];
  const float* bp2  = (const float*)d_in[17];
  const float* Wek  = (const float*)d_in[18];
  const float* Wev  = (const float*)d_in[19];
  const float* Wcomb= (const float*)d_in[20];
  const float* Wqh  = (const float*)d_in[21];
  const float* Wk1h = (const float*)d_in[22];
  const float* Wk2h = (const float*)d_in[23];
  const float* Wep  = (const float*)d_in[24];
  const float* Wres = (const float*)d_in[25];
  const float* P1   = (const float*)d_in[26];
  const float* P2   = (const float*)d_in[27];
  const float* Wf1a = (const float*)d_in[28];
  const float* bf1a = (const float*)d_in[29];
  const float* Wf2a = (const float*)d_in[30];
  const float* bf2a = (const float*)d_in[31];
  const float* Wf1b = (const float*)d_in[32];
  const float* bf1b = (const float*)d_in[33];
  const float* Wf2b = (const float*)d_in[34];
  const float* bf2b = (const float*)d_in[35];
  float* ws  = (float*)d_ws;
  float* out = (float*)d_out;

  k0a_ln <<<dim3(256),  dim3(128), 0, stream>>>(h, g_i, g_j, ws);
  k0b_qkv<<<dim3(1536), dim3(256), 0, stream>>>(Wq, Wk, Wv1, bv1, Wp1, bp1, ws);
  k0c_qk12<<<dim3(256), dim3(256), 0, stream>>>(x1, x2, Wqh, Wk1h, Wk2h, ws);
  k1_vp  <<<dim3(320),  dim3(256), 0, stream>>>(Wv2, bv2, Wp2, bp2, ws);
  k2_vw  <<<dim3(256),  dim3(256), 0, stream>>>(Wcomb, ws);
  k_cvt  <<<dim3(88),   dim3(256), 0, stream>>>(Wev, Wcomb, ws);
  k3_t   <<<dim3(512),  dim3(512), 0, stream>>>(t_ij, Wep, Wres, ws);
  k4_den <<<dim3(5120), dim3(256), 0, stream>>>(Wek, ws);
  k5_pass2<<<dim3(512), dim3(512), 0, stream>>>(x1, x2, r1, r2, ws);
  k6_tail<<<dim3(256),  dim3(256), 0, stream>>>(h, P1, P2, Wf1a, bf1a, Wf2a, bf2a, Wf1b, bf1b, Wf2b, bf2b, ws, out);
}